// Round 4
// baseline (411.664 us; speedup 1.0000x reference)
//
#include <hip/hip_runtime.h>
#include <stdint.h>

// ---------------------------------------------------------------------------
// AvgClicksPoolingInitializer  (B=8, I=16, C=256)
// Levels: L=0..3  w=128>>L, P=w*w, k=4<<L (scribble 512 / w)
// Bilinear half-pixel downsample 512->w lands exactly between two pixels in
// each dim => m[y][x] = 0.25*(S[r0][c0]+S[r0][c1]+S[r1][c0]+S[r1][c1]),
// r0 = k*y + k/2 - 1, c0 = k*x + k/2 - 1.   sel = (m > 0.5)  <=>  sum4 > 2.0
// ---------------------------------------------------------------------------

#define NI 16
#define NB 8
#define NC 256
#define PTOT 21760   // 16384+4096+1024+256

typedef __attribute__((ext_vector_type(8))) short bf16x8;
typedef __attribute__((ext_vector_type(4))) float f32x4;

__device__ __forceinline__ int level_off(int L) {
    return (L == 0) ? 0 : (L == 1) ? 16384 : (L == 2) ? 20480 : 21504;
}

__device__ __forceinline__ unsigned int ordered_bits(float v) {
    unsigned int u = __float_as_uint(v);
    return u ^ ((u >> 31) ? 0xFFFFFFFFu : 0x80000000u);
}

__device__ __forceinline__ unsigned short f2bf(float x) {   // RNE, finite inputs
    unsigned int u = __float_as_uint(x);
    u += 0x7FFFu + ((u >> 16) & 1u);
    return (unsigned short)(u >> 16);
}

// ---------------------------------------------------------------------------
// Kernel A: 4 waves/block = 4 instance-groups; each thread: 4 instances,
// ALL loads batched into registers. Per-(b,i) count via ballot+atomicAdd.
// grid (256, 8, 4): blockIdx.x over 64-pixel chunks, early-exit past P/64.
// ---------------------------------------------------------------------------
__global__ __launch_bounds__(256) void mask_kernel(
        const float* __restrict__ scr,          // (8,16,512,512)
        unsigned short* __restrict__ selmask,   // (8, PTOT)
        unsigned int* __restrict__ cntw) {      // (4,8,16) zero-init
    const int L = blockIdx.z, b = blockIdx.y;
    const int wl2 = 7 - L;
    const int w = 1 << wl2;
    const int P = 1 << (2 * wl2);
    const int k = 4 << L;
    if (blockIdx.x >= (P >> 6)) return;         // uniform block exit (before barrier)
    const int tx = threadIdx.x & 63;
    const int g  = threadIdx.x >> 6;            // instance group 0..3
    const int p = blockIdx.x * 64 + tx;
    const int y = p >> wl2, x = p & (w - 1);
    const int r0 = k * y + (k >> 1) - 1;
    const int c0 = k * x + (k >> 1) - 1;
    const int off = level_off(L);
    const float* Sg = scr + (size_t)(b * NI + g * 4) * 262144 + r0 * 512 + c0;

    float v[4];
    if (k == 4) {
        // c0 = 4x+1: aligned float4 at col 4x; need .y,.z
        float4 t0[4], t1[4];
#pragma unroll
        for (int j = 0; j < 4; ++j) {
            const float* Si = Sg + (size_t)j * 262144;
            t0[j] = *(const float4*)(Si - 1);
            t1[j] = *(const float4*)(Si - 1 + 512);
        }
#pragma unroll
        for (int j = 0; j < 4; ++j)
            v[j] = (t0[j].y + t0[j].z) + (t1[j].y + t1[j].z);
    } else {
        float a0[4], a1[4], a2[4], a3[4];
#pragma unroll
        for (int j = 0; j < 4; ++j) {
            const float* Si = Sg + (size_t)j * 262144;
            a0[j] = Si[0]; a1[j] = Si[1]; a2[j] = Si[512]; a3[j] = Si[513];
        }
#pragma unroll
        for (int j = 0; j < 4; ++j)
            v[j] = (a0[j] + a1[j]) + (a2[j] + a3[j]);
    }

    unsigned int nib = 0;
#pragma unroll
    for (int j = 0; j < 4; ++j) {
        const bool sel = v[j] > 2.0f;
        nib |= sel ? (1u << j) : 0u;
        const unsigned long long bal = __ballot(sel);
        if (tx == 0)
            atomicAdd(&cntw[(L * NB + b) * NI + g * 4 + j],
                      (unsigned int)__popcll(bal));
    }

    __shared__ unsigned int sh[4][64];
    sh[g][tx] = nib << (g * 4);
    __syncthreads();
    if (threadIdx.x < 64) {
        selmask[(size_t)b * PTOT + off + blockIdx.x * 64 + threadIdx.x] =
            (unsigned short)(sh[0][threadIdx.x] | sh[1][threadIdx.x] |
                             sh[2][threadIdx.x] | sh[3][threadIdx.x]);
    }
}

// ---------------------------------------------------------------------------
// Kernel A2 (lazy): per (L,b,i) block — ONLY if cnt==0, recompute resized
// values from scribbles and find first-index argmax. Early-exit otherwise.
// ---------------------------------------------------------------------------
__global__ __launch_bounds__(256) void lazy_argmax(
        const float* __restrict__ scr,
        const unsigned int* __restrict__ cntw,
        unsigned int* __restrict__ amaxp) {     // (4,8,16)
    const int g = blockIdx.x;                   // 512 groups
    __shared__ unsigned int need;
    if (threadIdx.x == 0) need = cntw[g];
    __syncthreads();
    if (need != 0) return;                      // common case: nothing to do

    const int L = g >> 7, b = (g >> 4) & 7, i = g & 15;
    const int wl2 = 7 - L;
    const int w = 1 << wl2;
    const int P = 1 << (2 * wl2);
    const int k = 4 << L;
    const float* Si = scr + (size_t)(b * NI + i) * 262144;
    const int t = threadIdx.x;

    unsigned long long key = 0ull;
    for (int p = t; p < P; p += 256) {
        const int y = p >> wl2, x = p & (w - 1);
        const int r0 = k * y + (k >> 1) - 1;
        const int c0 = k * x + (k >> 1) - 1;
        const float* S = Si + r0 * 512 + c0;
        const float v = (S[0] + S[1]) + (S[512] + S[513]);
        const unsigned long long kk =
            ((unsigned long long)ordered_bits(v) << 32)
          | (unsigned long long)(0xFFFFFFFFu - (unsigned int)p);
        if (kk > key) key = kk;
    }

    __shared__ unsigned long long sk[256];
    sk[t] = key;
    __syncthreads();
#pragma unroll
    for (int s = 128; s > 0; s >>= 1) {
        if (t < s) { if (sk[t + s] > sk[t]) sk[t] = sk[t + s]; }
        __syncthreads();
    }
    if (t == 0) amaxp[g] = 0xFFFFFFFFu - (unsigned int)(sk[0] & 0xFFFFFFFFull);
}

// ---------------------------------------------------------------------------
// Kernel B: LDS-free MFMA pooling.  S[i,c] = sum_p sel[i,p]*f[c,p]  per (L,b).
// One wave per (c-tile of 16, K-split of 8). Fragments loaded DIRECTLY from
// global in their native MFMA layout:
//   A[m=lane&15][k=quad*8+j] = bit m of selmask[p0+quad*8+j]   (16B/quad)
//   B[k=quad*8+j][n=lane&15] = f[c0+n][p0+quad*8+j]            (2 x float4)
// Partials to 8 disjoint planes (no atomics, no memset of sw).
// grid (32, 8, 4): x = ct*2 + splitpair, wave w -> split (x&1)*4+w.
// ---------------------------------------------------------------------------
__global__ __launch_bounds__(256) void pool_direct(
        const float* __restrict__ f0, const float* __restrict__ f1,
        const float* __restrict__ f2, const float* __restrict__ f3,
        const unsigned short* __restrict__ selmask,
        float* __restrict__ swp) {              // 8 planes of (4,8,16,256)
    const int L = blockIdx.z, b = blockIdx.y;
    const int ct = blockIdx.x >> 1;             // c-tile of 16: 0..15
    const int wv = threadIdx.x >> 6;
    const int split = (blockIdx.x & 1) * 4 + wv;  // 0..7
    const int lane = threadIdx.x & 63;
    const int n = lane & 15, quad = lane >> 4;
    const int P = 16384 >> (2 * L);
    const int steps = P >> 5;                   // K-steps of 32
    const float* fL = (L == 0) ? f0 : (L == 1) ? f1 : (L == 2) ? f2 : f3;
    const float* frow = fL + (size_t)(b * NC + ct * 16 + n) * P + quad * 8;
    const unsigned short* selb = selmask + (size_t)b * PTOT + level_off(L) + quad * 8;

    f32x4 acc = {0.f, 0.f, 0.f, 0.f};

#pragma unroll 2
    for (int s = split; s < steps; s += 8) {
        const int p0 = s * 32;
        const float4 u0 = *(const float4*)(frow + p0);
        const float4 u1 = *(const float4*)(frow + p0 + 4);
        const uint4  mv = *(const uint4*)(selb + p0);   // 8 ushorts

        bf16x8 bv;
        bv[0] = (short)f2bf(u0.x); bv[1] = (short)f2bf(u0.y);
        bv[2] = (short)f2bf(u0.z); bv[3] = (short)f2bf(u0.w);
        bv[4] = (short)f2bf(u1.x); bv[5] = (short)f2bf(u1.y);
        bv[6] = (short)f2bf(u1.z); bv[7] = (short)f2bf(u1.w);

        bf16x8 av;
        {
            const unsigned int uu[4] = {mv.x, mv.y, mv.z, mv.w};
#pragma unroll
            for (int j = 0; j < 4; ++j) {
                const unsigned int lo = uu[j] & 0xFFFFu, hi = uu[j] >> 16;
                av[2 * j]     = ((lo >> n) & 1u) ? (short)0x3F80 : (short)0;
                av[2 * j + 1] = ((hi >> n) & 1u) ? (short)0x3F80 : (short)0;
            }
        }
        acc = __builtin_amdgcn_mfma_f32_16x16x32_bf16(av, bv, acc, 0, 0, 0);
    }

    // epilogue: D[m=i][n=c]: col=lane&15, row=quad*4+r
    float* plane = swp + (size_t)split * (4 * NB * NI * NC);
    const int cg = ct * 16 + n;
#pragma unroll
    for (int r = 0; r < 4; ++r) {
        const int i = quad * 4 + r;
        plane[(size_t)((L * NB + b) * NI + i) * NC + cg] = acc[r];
    }
}

// ---------------------------------------------------------------------------
// Kernel C: out[b][i][c] = 0.25 * sum_L (cnt>0 ? (sum_split s)/cnt : gather)
// ---------------------------------------------------------------------------
__global__ __launch_bounds__(256) void final_kernel(
        const float* __restrict__ f0, const float* __restrict__ f1,
        const float* __restrict__ f2, const float* __restrict__ f3,
        const float* __restrict__ swp,
        const unsigned int* __restrict__ cntw,
        const unsigned int* __restrict__ amaxp,
        float* __restrict__ out) {
    const int nidx = blockIdx.x * 256 + threadIdx.x;   // 32768 total
    const int c = nidx & 255;
    const int bi = nidx >> 8;
    const int i = bi & (NI - 1);
    const int b = bi >> 4;
    const int PLANE = 4 * NB * NI * NC;
    float acc = 0.0f;
#pragma unroll
    for (int L = 0; L < 4; ++L) {
        const int g = (L * NB + b) * NI + i;
        const unsigned int cc = cntw[g];
        if (cc > 0) {
            float s = 0.0f;
            const size_t base = (size_t)g * NC + c;
#pragma unroll
            for (int sp = 0; sp < 8; ++sp) s += swp[(size_t)sp * PLANE + base];
            acc += s / (float)cc;
        } else {
            const unsigned int p = amaxp[g];
            const float* fL = (L == 0) ? f0 : (L == 1) ? f1 : (L == 2) ? f2 : f3;
            const int P = 16384 >> (2 * L);
            acc += fL[(size_t)(b * NC + c) * P + p];
        }
    }
    out[nidx] = acc * 0.25f;
}

extern "C" void kernel_launch(void* const* d_in, const int* in_sizes, int n_in,
                              void* d_out, int out_size, void* d_ws, size_t ws_size,
                              hipStream_t stream) {
    (void)in_sizes; (void)n_in; (void)out_size; (void)ws_size;
    const float* f0  = (const float*)d_in[0];   // (8,256,128,128)
    const float* f1  = (const float*)d_in[1];   // (8,256,64,64)
    const float* f2  = (const float*)d_in[2];   // (8,256,32,32)
    const float* f3  = (const float*)d_in[3];   // (8,256,16,16)
    const float* scr = (const float*)d_in[4];   // (8,16,512,512)
    float* out = (float*)d_out;                 // (8,16,256) fp32

    char* ws = (char*)d_ws;
    const size_t SWP_SZ = (size_t)8 * 4 * NB * NI * NC * 4;   // 4,194,304
    const size_t SEL_SZ = (size_t)NB * PTOT * 2;              //   348,160
    const size_t CNT_SZ = 512 * 4;
    // layout: [swp | selm | cntw | idxw]
    float*          swp  = (float*)ws;
    unsigned short* selm = (unsigned short*)(ws + SWP_SZ);
    unsigned int*   cntw = (unsigned int*)(ws + SWP_SZ + SEL_SZ);
    unsigned int*   idxw = (unsigned int*)(ws + SWP_SZ + SEL_SZ + CNT_SZ);

    hipMemsetAsync(cntw, 0, CNT_SZ, stream);    // only the 2 KB counters

    dim3 gA(256, NB, 4);
    mask_kernel<<<gA, 256, 0, stream>>>(scr, selm, cntw);

    lazy_argmax<<<512, 256, 0, stream>>>(scr, cntw, idxw);

    dim3 gB(32, NB, 4);
    pool_direct<<<gB, 256, 0, stream>>>(f0, f1, f2, f3, selm, swp);

    final_kernel<<<128, 256, 0, stream>>>(f0, f1, f2, f3, swp, cntw, idxw, out);
}

// Round 5
// 330.857 us; speedup vs baseline: 1.2442x; 1.2442x over previous
//
#include <hip/hip_runtime.h>
#include <stdint.h>

// ---------------------------------------------------------------------------
// AvgClicksPoolingInitializer  (B=8, I=16, C=256)
// Levels: L=0..3  w=128>>L, P=w*w, k=4<<L (scribble 512 / w)
// Bilinear half-pixel downsample 512->w lands exactly between two pixels in
// each dim => m[y][x] = 0.25*(S[r0][c0]+S[r0][c1]+S[r1][c0]+S[r1][c1]),
// r0 = k*y + k/2 - 1, c0 = k*x + k/2 - 1.   sel = (m > 0.5)  <=>  sum4 > 2.0
//
// History: cross-lane shuffles (R1), per-i load chains (R2), and device-scope
// atomics (R4) each cost 50-100 us in the mask pass. Keep it pure-streaming.
// ---------------------------------------------------------------------------

#define NI 16
#define NB 8
#define NC 256
#define PTOT 21760   // 16384+4096+1024+256

typedef __attribute__((ext_vector_type(8))) short bf16x8;
typedef __attribute__((ext_vector_type(4))) float f32x4;

__device__ __forceinline__ int level_off(int L) {
    return (L == 0) ? 0 : (L == 1) ? 16384 : (L == 2) ? 20480 : 21504;
}

__device__ __forceinline__ unsigned int ordered_bits(float v) {
    unsigned int u = __float_as_uint(v);
    return u ^ ((u >> 31) ? 0xFFFFFFFFu : 0x80000000u);
}

__device__ __forceinline__ unsigned short f2bf(float x) {   // RNE, finite inputs
    unsigned int u = __float_as_uint(x);
    u += 0x7FFFu + ((u >> 16) & 1u);
    return (unsigned short)(u >> 16);
}

// ---------------------------------------------------------------------------
// Kernel A: pure streaming. 4 waves/block = 4 instance-groups; each thread
// handles 4 instances with ALL loads batched (one latency round-trip).
// NO atomics / ballots / cross-lane ops — only the selmask store.
// grid (256, 8, 4): blockIdx.x over 64-pixel chunks, early-exit past P/64.
// ---------------------------------------------------------------------------
__global__ __launch_bounds__(256) void mask_kernel(
        const float* __restrict__ scr,          // (8,16,512,512)
        unsigned short* __restrict__ selmask) { // (8, PTOT)
    const int L = blockIdx.z, b = blockIdx.y;
    const int wl2 = 7 - L;
    const int w = 1 << wl2;
    const int P = 1 << (2 * wl2);
    const int k = 4 << L;
    if (blockIdx.x >= (P >> 6)) return;         // uniform block exit (before barrier)
    const int tx = threadIdx.x & 63;
    const int g  = threadIdx.x >> 6;            // instance group 0..3
    const int p = blockIdx.x * 64 + tx;
    const int y = p >> wl2, x = p & (w - 1);
    const int r0 = k * y + (k >> 1) - 1;
    const int c0 = k * x + (k >> 1) - 1;
    const int off = level_off(L);
    const float* Sg = scr + (size_t)(b * NI + g * 4) * 262144 + r0 * 512 + c0;

    float v[4];
    if (k == 4) {
        // c0 = 4x+1: aligned float4 at col 4x; need .y,.z
        float4 t0[4], t1[4];
#pragma unroll
        for (int j = 0; j < 4; ++j) {
            const float* Si = Sg + (size_t)j * 262144;
            t0[j] = *(const float4*)(Si - 1);
            t1[j] = *(const float4*)(Si - 1 + 512);
        }
#pragma unroll
        for (int j = 0; j < 4; ++j)
            v[j] = (t0[j].y + t0[j].z) + (t1[j].y + t1[j].z);
    } else {
        float a0[4], a1[4], a2[4], a3[4];
#pragma unroll
        for (int j = 0; j < 4; ++j) {
            const float* Si = Sg + (size_t)j * 262144;
            a0[j] = Si[0]; a1[j] = Si[1]; a2[j] = Si[512]; a3[j] = Si[513];
        }
#pragma unroll
        for (int j = 0; j < 4; ++j)
            v[j] = (a0[j] + a1[j]) + (a2[j] + a3[j]);
    }

    unsigned int nib = 0;
#pragma unroll
    for (int j = 0; j < 4; ++j)
        nib |= (v[j] > 2.0f) ? (1u << j) : 0u;

    __shared__ unsigned int sh[4][64];
    sh[g][tx] = nib << (g * 4);
    __syncthreads();
    if (threadIdx.x < 64) {
        selmask[(size_t)b * PTOT + off + blockIdx.x * 64 + threadIdx.x] =
            (unsigned short)(sh[0][threadIdx.x] | sh[1][threadIdx.x] |
                             sh[2][threadIdx.x] | sh[3][threadIdx.x]);
    }
}

// ---------------------------------------------------------------------------
// Kernel A1: per (L,b,i) block — popcount bit i of selmask (L2/L3-resident,
// ~4.5 MB total reads). Fully overwrites cntw: no memset needed.
// ---------------------------------------------------------------------------
__global__ __launch_bounds__(256) void count_kernel(
        const unsigned short* __restrict__ selmask,
        unsigned int* __restrict__ cntw) {      // (4,8,16)
    const int g = blockIdx.x;                   // 512 groups
    const int L = g >> 7, b = (g >> 4) & 7, i = g & 15;
    const int P = 16384 >> (2 * L);
    const uint4* base = (const uint4*)(selmask + (size_t)b * PTOT + level_off(L));
    const int t = threadIdx.x;

    unsigned int cnt = 0;
    for (int e = t; e < (P >> 3); e += 256) {   // 8 ushorts per uint4
        const uint4 v = base[e];
        const unsigned int u[4] = {v.x, v.y, v.z, v.w};
#pragma unroll
        for (int j = 0; j < 4; ++j) {
            cnt += (u[j] >> i) & 1u;
            cnt += (u[j] >> (16 + i)) & 1u;
        }
    }

    __shared__ unsigned int sc[256];
    sc[t] = cnt;
    __syncthreads();
#pragma unroll
    for (int s = 128; s > 0; s >>= 1) {
        if (t < s) sc[t] += sc[t + s];
        __syncthreads();
    }
    if (t == 0) cntw[g] = sc[0];
}

// ---------------------------------------------------------------------------
// Kernel A2 (lazy): per (L,b,i) block — ONLY if cnt==0, recompute resized
// values from scribbles and find first-index argmax. Early-exit otherwise.
// ---------------------------------------------------------------------------
__global__ __launch_bounds__(256) void lazy_argmax(
        const float* __restrict__ scr,
        const unsigned int* __restrict__ cntw,
        unsigned int* __restrict__ amaxp) {     // (4,8,16)
    const int g = blockIdx.x;                   // 512 groups
    __shared__ unsigned int need;
    if (threadIdx.x == 0) need = cntw[g];
    __syncthreads();
    if (need != 0) return;                      // common case: nothing to do

    const int L = g >> 7, b = (g >> 4) & 7, i = g & 15;
    const int wl2 = 7 - L;
    const int w = 1 << wl2;
    const int P = 1 << (2 * wl2);
    const int k = 4 << L;
    const float* Si = scr + (size_t)(b * NI + i) * 262144;
    const int t = threadIdx.x;

    unsigned long long key = 0ull;
    for (int p = t; p < P; p += 256) {
        const int y = p >> wl2, x = p & (w - 1);
        const int r0 = k * y + (k >> 1) - 1;
        const int c0 = k * x + (k >> 1) - 1;
        const float* S = Si + r0 * 512 + c0;
        const float v = (S[0] + S[1]) + (S[512] + S[513]);
        const unsigned long long kk =
            ((unsigned long long)ordered_bits(v) << 32)
          | (unsigned long long)(0xFFFFFFFFu - (unsigned int)p);
        if (kk > key) key = kk;
    }

    __shared__ unsigned long long sk[256];
    sk[t] = key;
    __syncthreads();
#pragma unroll
    for (int s = 128; s > 0; s >>= 1) {
        if (t < s) { if (sk[t + s] > sk[t]) sk[t] = sk[t + s]; }
        __syncthreads();
    }
    if (t == 0) amaxp[g] = 0xFFFFFFFFu - (unsigned int)(sk[0] & 0xFFFFFFFFull);
}

// ---------------------------------------------------------------------------
// Kernel B: LDS-free MFMA pooling.  S[i,c] = sum_p sel[i,p]*f[c,p]  per (L,b).
// One wave per (c-tile of 16, K-split of 8). Fragments loaded DIRECTLY from
// global in their native MFMA layout:
//   A[m=lane&15][k=quad*8+j] = bit m of selmask[p0+quad*8+j]   (16B/quad)
//   B[k=quad*8+j][n=lane&15] = f[c0+n][p0+quad*8+j]            (2 x float4)
// Partials to 8 disjoint planes (no atomics, no memset of sw).
// ---------------------------------------------------------------------------
__global__ __launch_bounds__(256) void pool_direct(
        const float* __restrict__ f0, const float* __restrict__ f1,
        const float* __restrict__ f2, const float* __restrict__ f3,
        const unsigned short* __restrict__ selmask,
        float* __restrict__ swp) {              // 8 planes of (4,8,16,256)
    const int L = blockIdx.z, b = blockIdx.y;
    const int ct = blockIdx.x >> 1;             // c-tile of 16: 0..15
    const int wv = threadIdx.x >> 6;
    const int split = (blockIdx.x & 1) * 4 + wv;  // 0..7
    const int lane = threadIdx.x & 63;
    const int n = lane & 15, quad = lane >> 4;
    const int P = 16384 >> (2 * L);
    const int steps = P >> 5;                   // K-steps of 32
    const float* fL = (L == 0) ? f0 : (L == 1) ? f1 : (L == 2) ? f2 : f3;
    const float* frow = fL + (size_t)(b * NC + ct * 16 + n) * P + quad * 8;
    const unsigned short* selb = selmask + (size_t)b * PTOT + level_off(L) + quad * 8;

    f32x4 acc = {0.f, 0.f, 0.f, 0.f};

#pragma unroll 2
    for (int s = split; s < steps; s += 8) {
        const int p0 = s * 32;
        const float4 u0 = *(const float4*)(frow + p0);
        const float4 u1 = *(const float4*)(frow + p0 + 4);
        const uint4  mv = *(const uint4*)(selb + p0);   // 8 ushorts

        bf16x8 bv;
        bv[0] = (short)f2bf(u0.x); bv[1] = (short)f2bf(u0.y);
        bv[2] = (short)f2bf(u0.z); bv[3] = (short)f2bf(u0.w);
        bv[4] = (short)f2bf(u1.x); bv[5] = (short)f2bf(u1.y);
        bv[6] = (short)f2bf(u1.z); bv[7] = (short)f2bf(u1.w);

        bf16x8 av;
        {
            const unsigned int uu[4] = {mv.x, mv.y, mv.z, mv.w};
#pragma unroll
            for (int j = 0; j < 4; ++j) {
                const unsigned int lo = uu[j] & 0xFFFFu, hi = uu[j] >> 16;
                av[2 * j]     = ((lo >> n) & 1u) ? (short)0x3F80 : (short)0;
                av[2 * j + 1] = ((hi >> n) & 1u) ? (short)0x3F80 : (short)0;
            }
        }
        acc = __builtin_amdgcn_mfma_f32_16x16x32_bf16(av, bv, acc, 0, 0, 0);
    }

    // epilogue: D[m=i][n=c]: col=lane&15, row=quad*4+r
    float* plane = swp + (size_t)split * (4 * NB * NI * NC);
    const int cg = ct * 16 + n;
#pragma unroll
    for (int r = 0; r < 4; ++r) {
        const int i = quad * 4 + r;
        plane[(size_t)((L * NB + b) * NI + i) * NC + cg] = acc[r];
    }
}

// ---------------------------------------------------------------------------
// Kernel C: out[b][i][c] = 0.25 * sum_L (cnt>0 ? (sum_split s)/cnt : gather)
// ---------------------------------------------------------------------------
__global__ __launch_bounds__(256) void final_kernel(
        const float* __restrict__ f0, const float* __restrict__ f1,
        const float* __restrict__ f2, const float* __restrict__ f3,
        const float* __restrict__ swp,
        const unsigned int* __restrict__ cntw,
        const unsigned int* __restrict__ amaxp,
        float* __restrict__ out) {
    const int nidx = blockIdx.x * 256 + threadIdx.x;   // 32768 total
    const int c = nidx & 255;
    const int bi = nidx >> 8;
    const int i = bi & (NI - 1);
    const int b = bi >> 4;
    const int PLANE = 4 * NB * NI * NC;
    float acc = 0.0f;
#pragma unroll
    for (int L = 0; L < 4; ++L) {
        const int g = (L * NB + b) * NI + i;
        const unsigned int cc = cntw[g];
        if (cc > 0) {
            float s = 0.0f;
            const size_t base = (size_t)g * NC + c;
#pragma unroll
            for (int sp = 0; sp < 8; ++sp) s += swp[(size_t)sp * PLANE + base];
            acc += s / (float)cc;
        } else {
            const unsigned int p = amaxp[g];
            const float* fL = (L == 0) ? f0 : (L == 1) ? f1 : (L == 2) ? f2 : f3;
            const int P = 16384 >> (2 * L);
            acc += fL[(size_t)(b * NC + c) * P + p];
        }
    }
    out[nidx] = acc * 0.25f;
}

extern "C" void kernel_launch(void* const* d_in, const int* in_sizes, int n_in,
                              void* d_out, int out_size, void* d_ws, size_t ws_size,
                              hipStream_t stream) {
    (void)in_sizes; (void)n_in; (void)out_size; (void)ws_size;
    const float* f0  = (const float*)d_in[0];   // (8,256,128,128)
    const float* f1  = (const float*)d_in[1];   // (8,256,64,64)
    const float* f2  = (const float*)d_in[2];   // (8,256,32,32)
    const float* f3  = (const float*)d_in[3];   // (8,256,16,16)
    const float* scr = (const float*)d_in[4];   // (8,16,512,512)
    float* out = (float*)d_out;                 // (8,16,256) fp32

    char* ws = (char*)d_ws;
    const size_t SWP_SZ = (size_t)8 * 4 * NB * NI * NC * 4;   // 4,194,304
    const size_t SEL_SZ = (size_t)NB * PTOT * 2;              //   348,160
    const size_t CNT_SZ = 512 * 4;
    // layout: [swp | selm | cntw | idxw]
    float*          swp  = (float*)ws;
    unsigned short* selm = (unsigned short*)(ws + SWP_SZ);
    unsigned int*   cntw = (unsigned int*)(ws + SWP_SZ + SEL_SZ);
    unsigned int*   idxw = (unsigned int*)(ws + SWP_SZ + SEL_SZ + CNT_SZ);

    dim3 gA(256, NB, 4);
    mask_kernel<<<gA, 256, 0, stream>>>(scr, selm);

    count_kernel<<<512, 256, 0, stream>>>(selm, cntw);

    lazy_argmax<<<512, 256, 0, stream>>>(scr, cntw, idxw);

    dim3 gB(32, NB, 4);
    pool_direct<<<gB, 256, 0, stream>>>(f0, f1, f2, f3, selm, swp);

    final_kernel<<<128, 256, 0, stream>>>(f0, f1, f2, f3, swp, cntw, idxw, out);
}

// Round 6
// 322.650 us; speedup vs baseline: 1.2759x; 1.0254x over previous
//
#include <hip/hip_runtime.h>
#include <stdint.h>

// ---------------------------------------------------------------------------
// AvgClicksPoolingInitializer  (B=8, I=16, C=256)
// Levels: L=0..3  w=128>>L, P=w*w, k=4<<L (scribble 512 / w)
// Bilinear half-pixel downsample 512->w lands exactly between two pixels in
// each dim => m[y][x] = 0.25*(S[r0][c0]+S[r0][c1]+S[r1][c0]+S[r1][c1]),
// r0 = k*y + k/2 - 1, c0 = k*x + k/2 - 1.   sel = (m > 0.5)  <=>  sum4 > 2.0
//
// History: cross-lane shuffles (R1), per-i serialized load chains (R2),
// device-scope atomics (R4), and an imbalanced L-major grid with shallow
// load batching (R5 pool) each cost 50-100 us. Rules: pure streaming, batch
// ALL loads per wave up front, balance work per wave across levels.
// ---------------------------------------------------------------------------

#define NI 16
#define NB 8
#define NC 256
#define PTOT 21760   // 16384+4096+1024+256

// per-level K-split counts (8 K-steps of 32 per wave, all levels)
#define SPL0 64
#define SPL1 16
#define SPL2 4
#define SPL3 1
#define NSP  85      // 64+16+4+1
#define PLANE (NB * NI * NC)   // 32768 floats per split-plane

typedef __attribute__((ext_vector_type(8))) short bf16x8;
typedef __attribute__((ext_vector_type(4))) float f32x4;

__device__ __forceinline__ int level_off(int L) {
    return (L == 0) ? 0 : (L == 1) ? 16384 : (L == 2) ? 20480 : 21504;
}

__device__ __forceinline__ unsigned int ordered_bits(float v) {
    unsigned int u = __float_as_uint(v);
    return u ^ ((u >> 31) ? 0xFFFFFFFFu : 0x80000000u);
}

__device__ __forceinline__ unsigned short f2bf(float x) {   // RNE, finite inputs
    unsigned int u = __float_as_uint(x);
    u += 0x7FFFu + ((u >> 16) & 1u);
    return (unsigned short)(u >> 16);
}

// ---------------------------------------------------------------------------
// Kernel A: pure streaming. 4 waves/block = 4 instance-groups; each thread
// handles 4 instances with ALL loads batched (one latency round-trip).
// NO atomics / ballots / cross-lane ops — only the selmask store.
// ---------------------------------------------------------------------------
__global__ __launch_bounds__(256) void mask_kernel(
        const float* __restrict__ scr,          // (8,16,512,512)
        unsigned short* __restrict__ selmask) { // (8, PTOT)
    const int L = blockIdx.z, b = blockIdx.y;
    const int wl2 = 7 - L;
    const int w = 1 << wl2;
    const int P = 1 << (2 * wl2);
    const int k = 4 << L;
    if (blockIdx.x >= (P >> 6)) return;         // uniform block exit (before barrier)
    const int tx = threadIdx.x & 63;
    const int g  = threadIdx.x >> 6;            // instance group 0..3
    const int p = blockIdx.x * 64 + tx;
    const int y = p >> wl2, x = p & (w - 1);
    const int r0 = k * y + (k >> 1) - 1;
    const int c0 = k * x + (k >> 1) - 1;
    const int off = level_off(L);
    const float* Sg = scr + (size_t)(b * NI + g * 4) * 262144 + r0 * 512 + c0;

    float v[4];
    if (k == 4) {
        // c0 = 4x+1: aligned float4 at col 4x; need .y,.z
        float4 t0[4], t1[4];
#pragma unroll
        for (int j = 0; j < 4; ++j) {
            const float* Si = Sg + (size_t)j * 262144;
            t0[j] = *(const float4*)(Si - 1);
            t1[j] = *(const float4*)(Si - 1 + 512);
        }
#pragma unroll
        for (int j = 0; j < 4; ++j)
            v[j] = (t0[j].y + t0[j].z) + (t1[j].y + t1[j].z);
    } else {
        float a0[4], a1[4], a2[4], a3[4];
#pragma unroll
        for (int j = 0; j < 4; ++j) {
            const float* Si = Sg + (size_t)j * 262144;
            a0[j] = Si[0]; a1[j] = Si[1]; a2[j] = Si[512]; a3[j] = Si[513];
        }
#pragma unroll
        for (int j = 0; j < 4; ++j)
            v[j] = (a0[j] + a1[j]) + (a2[j] + a3[j]);
    }

    unsigned int nib = 0;
#pragma unroll
    for (int j = 0; j < 4; ++j)
        nib |= (v[j] > 2.0f) ? (1u << j) : 0u;

    __shared__ unsigned int sh[4][64];
    sh[g][tx] = nib << (g * 4);
    __syncthreads();
    if (threadIdx.x < 64) {
        selmask[(size_t)b * PTOT + off + blockIdx.x * 64 + threadIdx.x] =
            (unsigned short)(sh[0][threadIdx.x] | sh[1][threadIdx.x] |
                             sh[2][threadIdx.x] | sh[3][threadIdx.x]);
    }
}

// ---------------------------------------------------------------------------
// Kernel B: LDS-free MFMA pooling, flat balanced grid.
// One wave per (L, b, c-tile of 16, split); every wave does exactly 8
// contiguous K-steps of 32. All 24 loads batched up front.
//   A[m=lane&15][k=quad*8+j] = bit m of selmask[p0+quad*8+j]
//   B[k=quad*8+j][n=lane&15] = f[c0+n][p0+quad*8+j]
// Partials to per-(L,split) planes; no atomics, no memset.
// waves: L0 8*16*64=8192, L1 2048, L2 512, L3 128 -> 10880 = 2720 blocks
// ---------------------------------------------------------------------------
__global__ __launch_bounds__(256) void pool_direct(
        const float* __restrict__ f0, const float* __restrict__ f1,
        const float* __restrict__ f2, const float* __restrict__ f3,
        const unsigned short* __restrict__ selmask,
        float* __restrict__ swp) {              // NSP planes of (8,16,256)
    const int wid = blockIdx.x * 4 + (threadIdx.x >> 6);
    const int lane = threadIdx.x & 63;
    const int n = lane & 15, quad = lane >> 4;

    int L, b, ct, sp, lvlbase;
    {
        int u = wid;
        if (u < 8192)              { L = 0; sp = u & 63; ct = (u >> 6) & 15; b = u >> 10; lvlbase = 0;  }
        else if ((u -= 8192) < 2048) { L = 1; sp = u & 15; ct = (u >> 4) & 15; b = u >> 8;  lvlbase = 64; }
        else if ((u -= 2048) < 512)  { L = 2; sp = u & 3;  ct = (u >> 2) & 15; b = u >> 6;  lvlbase = 80; }
        else { u -= 512;             L = 3; sp = 0;      ct = u & 15;        b = u >> 4;  lvlbase = 84; }
    }

    const int P = 16384 >> (2 * L);
    const float* fL = (L == 0) ? f0 : (L == 1) ? f1 : (L == 2) ? f2 : f3;
    const float* frow = fL + (size_t)(b * NC + ct * 16 + n) * P + quad * 8;
    const unsigned short* selb = selmask + (size_t)b * PTOT + level_off(L) + quad * 8;
    const int p00 = sp * 8 * 32;                // contiguous 8 K-steps

    // ---- batch ALL loads (one latency round-trip per wave)
    float4 uf[16];
    uint4  um[8];
#pragma unroll
    for (int j = 0; j < 8; ++j) {
        const int p0 = p00 + j * 32;
        uf[2 * j]     = *(const float4*)(frow + p0);
        uf[2 * j + 1] = *(const float4*)(frow + p0 + 4);
        um[j]         = *(const uint4*)(selb + p0);
    }

    f32x4 acc = {0.f, 0.f, 0.f, 0.f};
#pragma unroll
    for (int j = 0; j < 8; ++j) {
        bf16x8 bv;
        bv[0] = (short)f2bf(uf[2*j].x);   bv[1] = (short)f2bf(uf[2*j].y);
        bv[2] = (short)f2bf(uf[2*j].z);   bv[3] = (short)f2bf(uf[2*j].w);
        bv[4] = (short)f2bf(uf[2*j+1].x); bv[5] = (short)f2bf(uf[2*j+1].y);
        bv[6] = (short)f2bf(uf[2*j+1].z); bv[7] = (short)f2bf(uf[2*j+1].w);

        bf16x8 av;
        const unsigned int uu[4] = {um[j].x, um[j].y, um[j].z, um[j].w};
#pragma unroll
        for (int t = 0; t < 4; ++t) {
            const unsigned int lo = uu[t] & 0xFFFFu, hi = uu[t] >> 16;
            av[2 * t]     = ((lo >> n) & 1u) ? (short)0x3F80 : (short)0;
            av[2 * t + 1] = ((hi >> n) & 1u) ? (short)0x3F80 : (short)0;
        }
        acc = __builtin_amdgcn_mfma_f32_16x16x32_bf16(av, bv, acc, 0, 0, 0);
    }

    // ---- epilogue: D[m=i][n=c]: col=lane&15, row=quad*4+r
    float* plane = swp + (size_t)(lvlbase + sp) * PLANE;
    const int cg = ct * 16 + n;
#pragma unroll
    for (int r = 0; r < 4; ++r) {
        const int i = quad * 4 + r;
        plane[(size_t)(b * NI + i) * NC + cg] = acc[r];
    }
}

// ---------------------------------------------------------------------------
// Kernel A1: per (L,b,i) block — popcount bit i of selmask (L2-resident).
// Fully overwrites cntw: no memset needed.
// ---------------------------------------------------------------------------
__global__ __launch_bounds__(256) void count_kernel(
        const unsigned short* __restrict__ selmask,
        unsigned int* __restrict__ cntw) {      // (4,8,16)
    const int g = blockIdx.x;                   // 512 groups
    const int L = g >> 7, b = (g >> 4) & 7, i = g & 15;
    const int P = 16384 >> (2 * L);
    const uint4* base = (const uint4*)(selmask + (size_t)b * PTOT + level_off(L));
    const int t = threadIdx.x;

    unsigned int cnt = 0;
    for (int e = t; e < (P >> 3); e += 256) {   // 8 ushorts per uint4
        const uint4 v = base[e];
        const unsigned int u[4] = {v.x, v.y, v.z, v.w};
#pragma unroll
        for (int j = 0; j < 4; ++j) {
            cnt += (u[j] >> i) & 1u;
            cnt += (u[j] >> (16 + i)) & 1u;
        }
    }

    __shared__ unsigned int sc[256];
    sc[t] = cnt;
    __syncthreads();
#pragma unroll
    for (int s = 128; s > 0; s >>= 1) {
        if (t < s) sc[t] += sc[t + s];
        __syncthreads();
    }
    if (t == 0) cntw[g] = sc[0];
}

// ---------------------------------------------------------------------------
// Kernel A2 (lazy): per (L,b,i) block — ONLY if cnt==0, recompute resized
// values from scribbles and find first-index argmax. Early-exit otherwise.
// ---------------------------------------------------------------------------
__global__ __launch_bounds__(256) void lazy_argmax(
        const float* __restrict__ scr,
        const unsigned int* __restrict__ cntw,
        unsigned int* __restrict__ amaxp) {     // (4,8,16)
    const int g = blockIdx.x;                   // 512 groups
    __shared__ unsigned int need;
    if (threadIdx.x == 0) need = cntw[g];
    __syncthreads();
    if (need != 0) return;                      // common case: nothing to do

    const int L = g >> 7, b = (g >> 4) & 7, i = g & 15;
    const int wl2 = 7 - L;
    const int w = 1 << wl2;
    const int P = 1 << (2 * wl2);
    const int k = 4 << L;
    const float* Si = scr + (size_t)(b * NI + i) * 262144;
    const int t = threadIdx.x;

    unsigned long long key = 0ull;
    for (int p = t; p < P; p += 256) {
        const int y = p >> wl2, x = p & (w - 1);
        const int r0 = k * y + (k >> 1) - 1;
        const int c0 = k * x + (k >> 1) - 1;
        const float* S = Si + r0 * 512 + c0;
        const float v = (S[0] + S[1]) + (S[512] + S[513]);
        const unsigned long long kk =
            ((unsigned long long)ordered_bits(v) << 32)
          | (unsigned long long)(0xFFFFFFFFu - (unsigned int)p);
        if (kk > key) key = kk;
    }

    __shared__ unsigned long long sk[256];
    sk[t] = key;
    __syncthreads();
#pragma unroll
    for (int s = 128; s > 0; s >>= 1) {
        if (t < s) { if (sk[t + s] > sk[t]) sk[t] = sk[t + s]; }
        __syncthreads();
    }
    if (t == 0) amaxp[g] = 0xFFFFFFFFu - (unsigned int)(sk[0] & 0xFFFFFFFFull);
}

// ---------------------------------------------------------------------------
// Kernel C: out[b][i][c] = 0.25 * sum_L (cnt>0 ? (sum_split s)/cnt : gather)
// ---------------------------------------------------------------------------
__global__ __launch_bounds__(256) void final_kernel(
        const float* __restrict__ f0, const float* __restrict__ f1,
        const float* __restrict__ f2, const float* __restrict__ f3,
        const float* __restrict__ swp,
        const unsigned int* __restrict__ cntw,
        const unsigned int* __restrict__ amaxp,
        float* __restrict__ out) {
    const int nidx = blockIdx.x * 256 + threadIdx.x;   // 32768 total
    const int c = nidx & 255;
    const int bi = nidx >> 8;                   // = b*16 + i
    const int i = bi & (NI - 1);
    const int b = bi >> 4;
    const int lvlbase[4] = {0, 64, 80, 84};
    const int spl[4] = {SPL0, SPL1, SPL2, SPL3};
    float acc = 0.0f;
#pragma unroll
    for (int L = 0; L < 4; ++L) {
        const int g = (L * NB + b) * NI + i;
        const unsigned int cc = cntw[g];
        if (cc > 0) {
            float s = 0.0f;
            const size_t base = (size_t)bi * NC + c;
            for (int sp = 0; sp < spl[L]; ++sp)
                s += swp[(size_t)(lvlbase[L] + sp) * PLANE + base];
            acc += s / (float)cc;
        } else {
            const unsigned int p = amaxp[g];
            const float* fL = (L == 0) ? f0 : (L == 1) ? f1 : (L == 2) ? f2 : f3;
            const int P = 16384 >> (2 * L);
            acc += fL[(size_t)(b * NC + c) * P + p];
        }
    }
    out[nidx] = acc * 0.25f;
}

extern "C" void kernel_launch(void* const* d_in, const int* in_sizes, int n_in,
                              void* d_out, int out_size, void* d_ws, size_t ws_size,
                              hipStream_t stream) {
    (void)in_sizes; (void)n_in; (void)out_size; (void)ws_size;
    const float* f0  = (const float*)d_in[0];   // (8,256,128,128)
    const float* f1  = (const float*)d_in[1];   // (8,256,64,64)
    const float* f2  = (const float*)d_in[2];   // (8,256,32,32)
    const float* f3  = (const float*)d_in[3];   // (8,256,16,16)
    const float* scr = (const float*)d_in[4];   // (8,16,512,512)
    float* out = (float*)d_out;                 // (8,16,256) fp32

    char* ws = (char*)d_ws;
    const size_t SWP_SZ = (size_t)NSP * PLANE * 4;            // 11,141,120
    const size_t SEL_SZ = (size_t)NB * PTOT * 2;              //    348,160
    const size_t CNT_SZ = 512 * 4;
    // layout: [swp | selm | cntw | idxw]
    float*          swp  = (float*)ws;
    unsigned short* selm = (unsigned short*)(ws + SWP_SZ);
    unsigned int*   cntw = (unsigned int*)(ws + SWP_SZ + SEL_SZ);
    unsigned int*   idxw = (unsigned int*)(ws + SWP_SZ + SEL_SZ + CNT_SZ);

    dim3 gA(256, NB, 4);
    mask_kernel<<<gA, 256, 0, stream>>>(scr, selm);

    pool_direct<<<2720, 256, 0, stream>>>(f0, f1, f2, f3, selm, swp);

    count_kernel<<<512, 256, 0, stream>>>(selm, cntw);

    lazy_argmax<<<512, 256, 0, stream>>>(scr, cntw, idxw);

    final_kernel<<<128, 256, 0, stream>>>(f0, f1, f2, f3, swp, cntw, idxw, out);
}